// Round 12
// baseline (15.168 us; speedup 1.0000x reference)
//
#include <hip/hip_runtime.h>
#include <hip/hip_bf16.h>

#define H 1024
#define B 128

typedef unsigned short u16;
typedef unsigned int u32;
typedef __attribute__((ext_vector_type(8))) short bf16x8;
typedef __attribute__((ext_vector_type(4))) float f32x4;

static __device__ inline u16 f2bf(float x) {
    __hip_bfloat16 h = __float2bfloat16(x);   // RTNE -> v_cvt_pk_bf16_f32 pairs
    return __builtin_bit_cast(u16, h);
}
static __device__ inline u32 pack2(u16 a, u16 b) { return (u32)a | ((u32)b << 16); }

// ---- k1 -------------------------------------------------------------------
// blocks 0..255 : 4 U-rows each. Q[k][j] = exp(U[k][j]) / S[k], written in
//   pack-of-4 layout expUP4[k>>2][j][k&3] (bf16). Each wave owns a j-quarter
//   of all 4 rows; row sums via in-reg butterfly + 16-float LDS exchange.
//   No LDS transpose. All global ops coalesced.
// blocks 256..287: 4 A-rows each -> expA[b][k] = exp(A[b][k]) bf16 row-major.
__global__ __launch_bounds__(256) void k1(const float* __restrict__ A,
                                          const float* __restrict__ U,
                                          u16* __restrict__ expUP4,
                                          u16* __restrict__ expA) {
    const int t = threadIdx.x, w = t >> 6, l = t & 63;
    const int blk = blockIdx.x;
    if (blk < 256) {
        __shared__ float part[4][4];     // [row][wave]
        const int jbase = w * 256 + l;   // + m*64
        float e[4][4];                   // [row][m]
        float p[4] = {0.f, 0.f, 0.f, 0.f};
        #pragma unroll
        for (int r = 0; r < 4; ++r) {
            const float* Ur = U + (size_t)(blk * 4 + r) * H;
            #pragma unroll
            for (int m = 0; m < 4; ++m) {
                float v = __expf(Ur[jbase + m * 64]);
                e[r][m] = v;
                p[r] += v;
            }
        }
        #pragma unroll
        for (int r = 0; r < 4; ++r)
            #pragma unroll
            for (int off = 32; off > 0; off >>= 1)
                p[r] += __shfl_xor(p[r], off, 64);
        if (l == 0) {
            #pragma unroll
            for (int r = 0; r < 4; ++r) part[r][w] = p[r];
        }
        __syncthreads();
        float is[4];
        #pragma unroll
        for (int r = 0; r < 4; ++r)
            is[r] = 1.0f / (part[r][0] + part[r][1] + part[r][2] + part[r][3]);
        // store: expUP4[(blk*H + j)*4 .. +3] = rows 0..3 at column j
        u16* dst = expUP4 + (size_t)blk * H * 4;
        #pragma unroll
        for (int m = 0; m < 4; ++m) {
            const int j = jbase + m * 64;
            uint2 v;
            v.x = pack2(f2bf(e[0][m] * is[0]), f2bf(e[1][m] * is[1]));
            v.y = pack2(f2bf(e[2][m] * is[2]), f2bf(e[3][m] * is[3]));
            *reinterpret_cast<uint2*>(dst + (size_t)j * 4) = v;
        }
    } else {
        const int bb = (blk - 256) * 4;
        #pragma unroll
        for (int r = 0; r < 4; ++r) {
            const float* Ar = A + (size_t)(bb + r) * H;
            u16* Er = expA + (size_t)(bb + r) * H;
            const int j = w * 256 + l * 4;
            float4 a4 = *reinterpret_cast<const float4*>(Ar + j);
            ushort4 o = {f2bf(__expf(a4.x)), f2bf(__expf(a4.y)),
                         f2bf(__expf(a4.z)), f2bf(__expf(a4.w))};
            *reinterpret_cast<ushort4*>(Er + j) = o;
        }
    }
}

// ---- k2: out[b][j] = log( sum_k expA[b][k] * Q[k][j] ) --------------------
// grid (8,64) = 512 blocks x 512 threads = 8 waves; wave = kh (8-way K-split),
// 4 MFMA steps/wave. Pure load+MFMA loop, 1 barrier total.
__global__ __launch_bounds__(512) void k2(const u16* __restrict__ expA,
                                          const u16* __restrict__ expUP4,
                                          float* __restrict__ out) {
    __shared__ float red[8][4][68];      // [kh][reg][lane], 8.7 KB
    const int t = threadIdx.x, l = t & 63, kh = t >> 6;
    const int b0 = blockIdx.x * 16;
    const int j0 = blockIdx.y * 16;
    const int col  = j0 + (l & 15);
    const int arow = b0 + (l & 15);
    const int kg   = l >> 4;             // 0..3

    f32x4 acc = {0.f, 0.f, 0.f, 0.f};
    #pragma unroll
    for (int s = 0; s < 4; ++s) {
        const int kk = kh * 128 + s * 32 + kg * 8;
        bf16x8 af = *reinterpret_cast<const bf16x8*>(expA + (size_t)arow * H + kk);
        const int kq = kk >> 2;
        uint2 g0 = *reinterpret_cast<const uint2*>(expUP4 + ((size_t)kq * H + col) * 4);
        uint2 g1 = *reinterpret_cast<const uint2*>(expUP4 + ((size_t)(kq + 1) * H + col) * 4);
        uint4 bw = {g0.x, g0.y, g1.x, g1.y};
        bf16x8 bfv = __builtin_bit_cast(bf16x8, bw);
        acc = __builtin_amdgcn_mfma_f32_16x16x32_bf16(af, bfv, acc, 0, 0, 0);
    }

    #pragma unroll
    for (int r = 0; r < 4; ++r) red[kh][r][l] = acc[r];
    __syncthreads();

    if (t < 256) {
        const int row = t >> 4, c = t & 15;
        const int kg2 = row >> 2, r = row & 3;
        const int lane = kg2 * 16 + c;
        float v = 0.f;
        #pragma unroll
        for (int k = 0; k < 8; ++k) v += red[k][r][lane];
        out[(size_t)(b0 + row) * H + j0 + c] = __logf(v);
    }
}

extern "C" void kernel_launch(void* const* d_in, const int* in_sizes, int n_in,
                              void* d_out, int out_size, void* d_ws, size_t ws_size,
                              hipStream_t stream) {
    const float* A = (const float*)d_in[0];   // log_alpha (128 x 1024)
    const float* U = (const float*)d_in[1];   // unnormalized_tran (1024 x 1024)
    float* out = (float*)d_out;               // (128 x 1024) f32

    char* ws = (char*)d_ws;
    u16* expUP4 = (u16*)ws;                                  // 2 MB packed Q bf16
    u16* expA   = (u16*)(ws + (size_t)2 * 1024 * 1024);      // 256 KB exp(A) bf16

    k1<<<288, 256, 0, stream>>>(A, U, expUP4, expA);
    dim3 g(B / 16, H / 16);                   // (8, 64) = 512 blocks
    k2<<<g, 512, 0, stream>>>(expA, expUP4, out);
}

// Round 13
// 14.760 us; speedup vs baseline: 1.0276x; 1.0276x over previous
//
#include <hip/hip_runtime.h>
#include <hip/hip_bf16.h>

#define H 1024
#define B 128

typedef unsigned short u16;
typedef unsigned int u32;
typedef __attribute__((ext_vector_type(8))) short bf16x8;
typedef __attribute__((ext_vector_type(4))) float f32x4;

static __device__ inline u16 f2bf(float x) {
    __hip_bfloat16 h = __float2bfloat16(x);   // RTNE -> v_cvt_pk_bf16_f32 pairs
    return __builtin_bit_cast(u16, h);
}
static __device__ inline u32 pack2(u16 a, u16 b) { return (u32)a | ((u32)b << 16); }

// ---- k1: 256 blocks x 256 threads, uniform work, no tail ------------------
// Each block: 4 U-rows -> Q[k][j] = exp(U[k][j])/S[k], pack-of-4 layout
//   expUP4[k>>2][j][k&3] (bf16), written reg-direct (two uint4 stores/lane).
// Plus a 512-element slice of A -> expA[.] = bf16(exp(A[.])) row-major.
__global__ __launch_bounds__(256) void k1(const float* __restrict__ A,
                                          const float* __restrict__ U,
                                          u16* __restrict__ expUP4,
                                          u16* __restrict__ expA) {
    const int t = threadIdx.x, w = t >> 6, l = t & 63;
    const int blk = blockIdx.x;
    __shared__ float part[4][4];     // [row][wave]

    // U part: 4 rows, lane owns j = t*4 .. t*4+3
    const int j4 = t * 4;
    float e[4][4];
    float p[4];
    #pragma unroll
    for (int r = 0; r < 4; ++r) {
        float4 u4 = *reinterpret_cast<const float4*>(U + (size_t)(blk * 4 + r) * H + j4);
        e[r][0] = __expf(u4.x); e[r][1] = __expf(u4.y);
        e[r][2] = __expf(u4.z); e[r][3] = __expf(u4.w);
        p[r] = e[r][0] + e[r][1] + e[r][2] + e[r][3];
    }
    #pragma unroll
    for (int r = 0; r < 4; ++r)
        #pragma unroll
        for (int off = 32; off > 0; off >>= 1)
            p[r] += __shfl_xor(p[r], off, 64);
    if (l == 0) {
        #pragma unroll
        for (int r = 0; r < 4; ++r) part[r][w] = p[r];
    }
    __syncthreads();
    float is[4];
    #pragma unroll
    for (int r = 0; r < 4; ++r)
        is[r] = 1.0f / (part[r][0] + part[r][1] + part[r][2] + part[r][3]);

    // pack-of-4 store: block owns k-quad `blk`; column j gets rows 0..3
    {
        u16* dst = expUP4 + (size_t)blk * H * 4;
        u32 wv[4][2];
        #pragma unroll
        for (int m = 0; m < 4; ++m) {
            wv[m][0] = pack2(f2bf(e[0][m] * is[0]), f2bf(e[1][m] * is[1]));
            wv[m][1] = pack2(f2bf(e[2][m] * is[2]), f2bf(e[3][m] * is[3]));
        }
        uint4 s0 = {wv[0][0], wv[0][1], wv[1][0], wv[1][1]};
        uint4 s1 = {wv[2][0], wv[2][1], wv[3][0], wv[3][1]};
        uint4* ob = reinterpret_cast<uint4*>(dst + (size_t)j4 * 4);
        ob[0] = s0;
        ob[1] = s1;
    }

    // A part: flat slice [blk*512, blk*512+512), 2 elements/thread
    {
        const size_t off = (size_t)blk * 512 + t * 2;
        float2 a2 = *reinterpret_cast<const float2*>(A + off);
        ushort2 o = {f2bf(__expf(a2.x)), f2bf(__expf(a2.y))};
        *reinterpret_cast<ushort2*>(expA + off) = o;
    }
}

// ---- k2: out[b][j] = log( sum_k expA[b][k] * Q[k][j] ) --------------------
// grid (8,32) = 256 blocks x 512 threads = 8 waves: kh in 0..3 (K-split),
// jh in 0..1. Pure load+MFMA K-loop: no exp, no staging, no barriers.
__global__ __launch_bounds__(512) void k2(const u16* __restrict__ expA,
                                          const u16* __restrict__ expUP4,
                                          float* __restrict__ out) {
    __shared__ float red[3][2][16][16];  // kh=1..3 partials
    const int t = threadIdx.x, l = t & 63, w = t >> 6;
    const int jh = w & 1, kh = w >> 1;
    const int b0 = blockIdx.x * 16;
    const int j0 = blockIdx.y * 32;
    const int col  = j0 + jh * 16 + (l & 15);
    const int arow = b0 + (l & 15);
    const int kg   = l >> 4;             // 0..3

    f32x4 acc = {0.f, 0.f, 0.f, 0.f};
    #pragma unroll
    for (int s = 0; s < 8; ++s) {
        const int kk = s * 128 + kh * 32 + kg * 8;
        bf16x8 af = *reinterpret_cast<const bf16x8*>(expA + (size_t)arow * H + kk);
        const int kq = kk >> 2;
        uint2 g0 = *reinterpret_cast<const uint2*>(expUP4 + ((size_t)kq * H + col) * 4);
        uint2 g1 = *reinterpret_cast<const uint2*>(expUP4 + ((size_t)(kq + 1) * H + col) * 4);
        uint4 bw = {g0.x, g0.y, g1.x, g1.y};
        bf16x8 bfv = __builtin_bit_cast(bf16x8, bw);
        acc = __builtin_amdgcn_mfma_f32_16x16x32_bf16(af, bfv, acc, 0, 0, 0);
    }

    if (kh != 0) {
        #pragma unroll
        for (int r = 0; r < 4; ++r)
            red[kh - 1][jh][(l >> 4) * 4 + r][l & 15] = acc[r];
    }
    __syncthreads();
    if (kh == 0) {
        #pragma unroll
        for (int r = 0; r < 4; ++r) {
            const int row = (l >> 4) * 4 + r;
            const float v = acc[r] + red[0][jh][row][l & 15]
                                   + red[1][jh][row][l & 15]
                                   + red[2][jh][row][l & 15];
            out[(size_t)(b0 + row) * H + col] = __logf(v);
        }
    }
}

extern "C" void kernel_launch(void* const* d_in, const int* in_sizes, int n_in,
                              void* d_out, int out_size, void* d_ws, size_t ws_size,
                              hipStream_t stream) {
    const float* A = (const float*)d_in[0];   // log_alpha (128 x 1024)
    const float* U = (const float*)d_in[1];   // unnormalized_tran (1024 x 1024)
    float* out = (float*)d_out;               // (128 x 1024) f32

    char* ws = (char*)d_ws;
    u16* expUP4 = (u16*)ws;                                  // 2 MB packed Q bf16
    u16* expA   = (u16*)(ws + (size_t)2 * 1024 * 1024);      // 256 KB exp(A) bf16

    k1<<<256, 256, 0, stream>>>(A, U, expUP4, expA);
    dim3 g(B / 16, H / 32);                   // (8, 32) = 256 blocks
    k2<<<g, 512, 0, stream>>>(expA, expUP4, out);
}